// Round 12
// baseline (183.173 us; speedup 1.0000x reference)
//
#include <hip/hip_runtime.h>
#include <math.h>

#define N_NODES 20000
#define E_EDGES 320000
#define TOT_E   (E_EDGES + N_NODES)
#define DHID    256
#define NHEAD   4
#define ECAP    128   // edges staged in LDS per chunk per dst
#define EB_K    ((TOT_E + 255) / 256)   // 1329 scatter blocks
#define GB_K    (N_NODES / 32)          // 625 gemm blocks

typedef float f32x4 __attribute__((ext_vector_type(4)));
typedef short short8 __attribute__((ext_vector_type(8)));
typedef unsigned short ushort;

// ---------- helpers ----------
__device__ __forceinline__ float wave_sum(float v) {
#pragma unroll
  for (int off = 32; off; off >>= 1) v += __shfl_xor(v, off);
  return v;
}
__device__ __forceinline__ ushort f2bf(float f) {  // RNE f32 -> bf16
  unsigned u = __float_as_uint(f);
  u += 0x7fffu + ((u >> 16) & 1u);
  return (ushort)(u >> 16);
}
__device__ __forceinline__ float bflo(unsigned u) {
  return __uint_as_float(u << 16);
}
__device__ __forceinline__ float bfhi(unsigned u) {
  return __uint_as_float(u & 0xffff0000u);
}

// ---------- CSR build ----------
__global__ void hist_kernel(const int* __restrict__ ei, int* __restrict__ deg) {
  int e = blockIdx.x * blockDim.x + threadIdx.x;
  if (e >= TOT_E) return;
  int dst = (e < E_EDGES) ? ei[E_EDGES + e] : (e - E_EDGES);
  atomicAdd(&deg[dst], 1);
}

// single-block scan: 1024 threads x 20 elems
__global__ __launch_bounds__(1024)
void scan_kernel(const int* __restrict__ deg, int* __restrict__ rowp,
                 int* __restrict__ cur) {
  __shared__ int wsum[16];
  const int t = threadIdx.x;
  const int lane = t & 63, w = t >> 6;
  const int base = t * 20;
  int vals[20];
  int sum = 0;
#pragma unroll
  for (int k = 0; k < 20; ++k) {
    int i = base + k;
    int v = (i < N_NODES) ? deg[i] : 0;
    vals[k] = v;
    sum += v;
  }
  int inc = sum;
#pragma unroll
  for (int off = 1; off < 64; off <<= 1) {
    int u = __shfl_up(inc, off);
    if (lane >= off) inc += u;
  }
  if (lane == 63) wsum[w] = inc;
  __syncthreads();
  int add = 0;
#pragma unroll
  for (int k = 0; k < 16; ++k)
    if (k < w) add += wsum[k];
  int run = add + inc - sum;  // exclusive prefix for this thread's chunk
#pragma unroll
  for (int k = 0; k < 20; ++k) {
    int i = base + k;
    if (i < N_NODES) {
      rowp[i] = run;
      cur[i] = run;
      run += vals[k];
    }
  }
  if (t == 0) rowp[N_NODES] = TOT_E;
}

// ---------- conversions + deg zeroing (one grid) ----------
__global__ __launch_bounds__(256)
void conv_inputs_kernel(const float* __restrict__ W1, const float* __restrict__ W2,
                        const float* __restrict__ x, ushort* __restrict__ Wt1,
                        ushort* __restrict__ Wt2, ushort* __restrict__ xb,
                        int* __restrict__ deg) {
  const int b = blockIdx.x;
  if (b < 512) {
    const float* W = (b < 256) ? W1 : W2;
    ushort* Wt = (b < 256) ? Wt1 : Wt2;
    const int n = b & 255;
    const int k = threadIdx.x;
    Wt[n * 256 + k] = f2bf(W[k * 256 + n]);
  } else if (b < 512 + N_NODES * 256 / 8 / 256) {
    int idx = (b - 512) * 256 + threadIdx.x;  // granule of 8
    size_t base = (size_t)idx * 8;
    float4 a = *reinterpret_cast<const float4*>(x + base);
    float4 c = *reinterpret_cast<const float4*>(x + base + 4);
    short8 o;
    o[0] = f2bf(a.x); o[1] = f2bf(a.y); o[2] = f2bf(a.z); o[3] = f2bf(a.w);
    o[4] = f2bf(c.x); o[5] = f2bf(c.y); o[6] = f2bf(c.z); o[7] = f2bf(c.w);
    *reinterpret_cast<short8*>(xb + base) = o;
  } else {
    int idx = (b - (512 + N_NODES * 256 / 8 / 256)) * 256 + threadIdx.x;
    if (idx < N_NODES) deg[idx] = 0;
  }
}

// ---------- FUSED scatter (blocks 0..EB_K-1) + bf16-MFMA GEMM-with-alpha ----
// (blocks EB_K..EB_K+GB_K-1). Both depend only on conv+scan outputs.
__global__ __launch_bounds__(256)
void scatter_gemm_kernel(const int* __restrict__ ei, int* __restrict__ cur,
                         int* __restrict__ colb, const ushort* __restrict__ Ab,
                         const ushort* __restrict__ Wt, const float* __restrict__ asrc,
                         const float* __restrict__ adst, ushort* __restrict__ hout,
                         float* __restrict__ as_, float* __restrict__ ad_) {
  __shared__ ushort hs[32 * 256];  // 16 KB repack buffer (gemm path only)

  if (blockIdx.x < EB_K) {
    int e = blockIdx.x * 256 + threadIdx.x;
    if (e < TOT_E) {
      int src, dst;
      if (e < E_EDGES) { src = ei[e]; dst = ei[E_EDGES + e]; }
      else             { src = dst = e - E_EDGES; }
      int pos = atomicAdd(&cur[dst], 1);
      colb[pos] = src;
    }
    return;
  }

  const int t = threadIdx.x;
  const int w = t >> 6;
  const int l = t & 63;
  const int row0 = (blockIdx.x - EB_K) * 32;

  const ushort* abase = Ab + (size_t)(row0 + (l & 15)) * 256 + ((l >> 4) * 8);
  const ushort* bbase = Wt + (size_t)(w * 64 + (l & 15)) * 256 + ((l >> 4) * 8);

  f32x4 acc[2][4];
#pragma unroll
  for (int i = 0; i < 2; ++i)
#pragma unroll
    for (int j = 0; j < 4; ++j) acc[i][j] = (f32x4){0.f, 0.f, 0.f, 0.f};

  short8 a0 = *reinterpret_cast<const short8*>(abase);
  short8 a1 = *reinterpret_cast<const short8*>(abase + 16 * 256);
  short8 b0 = *reinterpret_cast<const short8*>(bbase);
  short8 b1 = *reinterpret_cast<const short8*>(bbase + 16 * 256);
  short8 b2 = *reinterpret_cast<const short8*>(bbase + 32 * 256);
  short8 b3 = *reinterpret_cast<const short8*>(bbase + 48 * 256);
#pragma unroll
  for (int kk = 0; kk < 256; kk += 32) {
    short8 na0, na1, nb0, nb1, nb2, nb3;
    if (kk + 32 < 256) {
      na0 = *reinterpret_cast<const short8*>(abase + kk + 32);
      na1 = *reinterpret_cast<const short8*>(abase + 16 * 256 + kk + 32);
      nb0 = *reinterpret_cast<const short8*>(bbase + kk + 32);
      nb1 = *reinterpret_cast<const short8*>(bbase + 16 * 256 + kk + 32);
      nb2 = *reinterpret_cast<const short8*>(bbase + 32 * 256 + kk + 32);
      nb3 = *reinterpret_cast<const short8*>(bbase + 48 * 256 + kk + 32);
    }
    acc[0][0] = __builtin_amdgcn_mfma_f32_16x16x32_bf16(a0, b0, acc[0][0], 0, 0, 0);
    acc[0][1] = __builtin_amdgcn_mfma_f32_16x16x32_bf16(a0, b1, acc[0][1], 0, 0, 0);
    acc[0][2] = __builtin_amdgcn_mfma_f32_16x16x32_bf16(a0, b2, acc[0][2], 0, 0, 0);
    acc[0][3] = __builtin_amdgcn_mfma_f32_16x16x32_bf16(a0, b3, acc[0][3], 0, 0, 0);
    acc[1][0] = __builtin_amdgcn_mfma_f32_16x16x32_bf16(a1, b0, acc[1][0], 0, 0, 0);
    acc[1][1] = __builtin_amdgcn_mfma_f32_16x16x32_bf16(a1, b1, acc[1][1], 0, 0, 0);
    acc[1][2] = __builtin_amdgcn_mfma_f32_16x16x32_bf16(a1, b2, acc[1][2], 0, 0, 0);
    acc[1][3] = __builtin_amdgcn_mfma_f32_16x16x32_bf16(a1, b3, acc[1][3], 0, 0, 0);
    if (kk + 32 < 256) {
      a0 = na0; a1 = na1; b0 = nb0; b1 = nb1; b2 = nb2; b3 = nb3;
    }
  }

  // ---- alpha epilogue ----
  float asj[4], adj[4];
#pragma unroll
  for (int j = 0; j < 4; ++j) {
    asj[j] = asrc[w * 64 + j * 16 + (l & 15)];
    adj[j] = adst[w * 64 + j * 16 + (l & 15)];
  }
#pragma unroll
  for (int i = 0; i < 2; ++i) {
#pragma unroll
    for (int q = 0; q < 4; ++q) {
      float ps = 0.f, pd = 0.f;
#pragma unroll
      for (int j = 0; j < 4; ++j) {
        ps += acc[i][j][q] * asj[j];
        pd += acc[i][j][q] * adj[j];
      }
#pragma unroll
      for (int off = 1; off < 16; off <<= 1) {
        ps += __shfl_xor(ps, off);
        pd += __shfl_xor(pd, off);
      }
      int row = row0 + i * 16 + (l >> 4) * 4 + q;
      if ((l & 15) == 0) {
        as_[row * 4 + w] = ps;
        ad_[row * 4 + w] = pd;
      }
    }
  }

  // ---- h repack: fragments -> LDS bf16 -> coalesced global ----
#pragma unroll
  for (int i = 0; i < 2; ++i)
#pragma unroll
    for (int j = 0; j < 4; ++j)
#pragma unroll
      for (int q = 0; q < 4; ++q) {
        int row = i * 16 + (l >> 4) * 4 + q;
        int col = w * 64 + j * 16 + (l & 15);
        hs[row * 256 + col] = f2bf(acc[i][j][q]);
      }
  __syncthreads();
#pragma unroll
  for (int g = 0; g < 4; ++g) {
    int gi = g * 256 + t;
    int row = gi >> 5;
    int slot = gi & 31;
    *reinterpret_cast<short8*>(hout + (size_t)(row0 + row) * 256 + slot * 8) =
        *reinterpret_cast<const short8*>(&hs[row * 256 + slot * 8]);
  }
}

// ---------- standalone GEMM (layer 2 uses this) ----------
__global__ __launch_bounds__(256)
void gemm_alpha_kernel(const ushort* __restrict__ Ab, const ushort* __restrict__ Wt,
                       const float* __restrict__ asrc, const float* __restrict__ adst,
                       ushort* __restrict__ hout, float* __restrict__ as_,
                       float* __restrict__ ad_) {
  __shared__ ushort hs[32 * 256];

  const int t = threadIdx.x;
  const int w = t >> 6;
  const int l = t & 63;
  const int row0 = blockIdx.x * 32;

  const ushort* abase = Ab + (size_t)(row0 + (l & 15)) * 256 + ((l >> 4) * 8);
  const ushort* bbase = Wt + (size_t)(w * 64 + (l & 15)) * 256 + ((l >> 4) * 8);

  f32x4 acc[2][4];
#pragma unroll
  for (int i = 0; i < 2; ++i)
#pragma unroll
    for (int j = 0; j < 4; ++j) acc[i][j] = (f32x4){0.f, 0.f, 0.f, 0.f};

  short8 a0 = *reinterpret_cast<const short8*>(abase);
  short8 a1 = *reinterpret_cast<const short8*>(abase + 16 * 256);
  short8 b0 = *reinterpret_cast<const short8*>(bbase);
  short8 b1 = *reinterpret_cast<const short8*>(bbase + 16 * 256);
  short8 b2 = *reinterpret_cast<const short8*>(bbase + 32 * 256);
  short8 b3 = *reinterpret_cast<const short8*>(bbase + 48 * 256);
#pragma unroll
  for (int kk = 0; kk < 256; kk += 32) {
    short8 na0, na1, nb0, nb1, nb2, nb3;
    if (kk + 32 < 256) {
      na0 = *reinterpret_cast<const short8*>(abase + kk + 32);
      na1 = *reinterpret_cast<const short8*>(abase + 16 * 256 + kk + 32);
      nb0 = *reinterpret_cast<const short8*>(bbase + kk + 32);
      nb1 = *reinterpret_cast<const short8*>(bbase + 16 * 256 + kk + 32);
      nb2 = *reinterpret_cast<const short8*>(bbase + 32 * 256 + kk + 32);
      nb3 = *reinterpret_cast<const short8*>(bbase + 48 * 256 + kk + 32);
    }
    acc[0][0] = __builtin_amdgcn_mfma_f32_16x16x32_bf16(a0, b0, acc[0][0], 0, 0, 0);
    acc[0][1] = __builtin_amdgcn_mfma_f32_16x16x32_bf16(a0, b1, acc[0][1], 0, 0, 0);
    acc[0][2] = __builtin_amdgcn_mfma_f32_16x16x32_bf16(a0, b2, acc[0][2], 0, 0, 0);
    acc[0][3] = __builtin_amdgcn_mfma_f32_16x16x32_bf16(a0, b3, acc[0][3], 0, 0, 0);
    acc[1][0] = __builtin_amdgcn_mfma_f32_16x16x32_bf16(a1, b0, acc[1][0], 0, 0, 0);
    acc[1][1] = __builtin_amdgcn_mfma_f32_16x16x32_bf16(a1, b1, acc[1][1], 0, 0, 0);
    acc[1][2] = __builtin_amdgcn_mfma_f32_16x16x32_bf16(a1, b2, acc[1][2], 0, 0, 0);
    acc[1][3] = __builtin_amdgcn_mfma_f32_16x16x32_bf16(a1, b3, acc[1][3], 0, 0, 0);
    if (kk + 32 < 256) {
      a0 = na0; a1 = na1; b0 = nb0; b1 = nb1; b2 = nb2; b3 = nb3;
    }
  }

  float asj[4], adj[4];
#pragma unroll
  for (int j = 0; j < 4; ++j) {
    asj[j] = asrc[w * 64 + j * 16 + (l & 15)];
    adj[j] = adst[w * 64 + j * 16 + (l & 15)];
  }
#pragma unroll
  for (int i = 0; i < 2; ++i) {
#pragma unroll
    for (int q = 0; q < 4; ++q) {
      float ps = 0.f, pd = 0.f;
#pragma unroll
      for (int j = 0; j < 4; ++j) {
        ps += acc[i][j][q] * asj[j];
        pd += acc[i][j][q] * adj[j];
      }
#pragma unroll
      for (int off = 1; off < 16; off <<= 1) {
        ps += __shfl_xor(ps, off);
        pd += __shfl_xor(pd, off);
      }
      int row = row0 + i * 16 + (l >> 4) * 4 + q;
      if ((l & 15) == 0) {
        as_[row * 4 + w] = ps;
        ad_[row * 4 + w] = pd;
      }
    }
  }

#pragma unroll
  for (int i = 0; i < 2; ++i)
#pragma unroll
    for (int j = 0; j < 4; ++j)
#pragma unroll
      for (int q = 0; q < 4; ++q) {
        int row = i * 16 + (l >> 4) * 4 + q;
        int col = w * 64 + j * 16 + (l & 15);
        hs[row * 256 + col] = f2bf(acc[i][j][q]);
      }
  __syncthreads();
#pragma unroll
  for (int g = 0; g < 4; ++g) {
    int gi = g * 256 + t;
    int row = gi >> 5;
    int slot = gi & 31;
    *reinterpret_cast<short8*>(hout + (size_t)(row0 + row) * 256 + slot * 8) =
        *reinterpret_cast<const short8*>(&hs[row * 256 + slot * 8]);
  }
}

// ---------- FUSED attn softmax + gather + bias + LN (+resid) + ELU (+score) ----
// (unchanged from round 11)
__global__ __launch_bounds__(256)
void attn_gather_ln_kernel(const ushort* __restrict__ h, const float* __restrict__ as_,
                           const float* __restrict__ ad_, const int* __restrict__ rowp,
                           const int* __restrict__ colb, const float* __restrict__ bias,
                           const float* __restrict__ gamma, const float* __restrict__ beta,
                           const ushort* __restrict__ residb, ushort* __restrict__ outb,
                           const float* __restrict__ aw, const float* __restrict__ ab,
                           float* __restrict__ score) {
  __shared__ float ew[4][ECAP][NHEAD];  // 8 KB
  __shared__ int   sidx[4][ECAP];       // 2 KB

  const int t = threadIdx.x;
  const int wd = t >> 6;
  const int d = blockIdx.x * 4 + wd;
  const int l = t & 63;
  const int start = rowp[d];
  const int deg = rowp[d + 1] - start;
  const int* cb = colb + start;

  const int e16 = l >> 2, hh = l & 3;
  const float adv = ad_[d * 4 + hh];
  const int gh = l >> 4;
  const int c0 = l * 4;
  const ushort* hrow = h + c0;

  float zpart = 0.f;
  float a0 = 0.f, a1 = 0.f, a2 = 0.f, a3 = 0.f;

  for (int base = 0; base < deg; base += ECAP) {
    const int cnt = min(deg - base, ECAP);
    for (int i = e16; i < cnt; i += 16) {
      int s = cb[base + i];
      if (hh == 0) sidx[wd][i] = s;
      float e = as_[s * 4 + hh] + adv;
      e = (e >= 0.f) ? e : 0.2f * e;
      e = fminf(e, 60.f);
      float wv = __expf(e);
      ew[wd][i][hh] = wv;
      zpart += wv;
    }
    int i = 0;
    for (; i + 8 <= cnt; i += 8) {
      int ss[8]; float ww[8]; uint2 hv[8];
#pragma unroll
      for (int k = 0; k < 8; ++k) { ss[k] = sidx[wd][i + k]; ww[k] = ew[wd][i + k][gh]; }
#pragma unroll
      for (int k = 0; k < 8; ++k)
        hv[k] = *reinterpret_cast<const uint2*>(hrow + (size_t)ss[k] * 256);
#pragma unroll
      for (int k = 0; k < 8; ++k) {
        a0 += ww[k] * bflo(hv[k].x); a1 += ww[k] * bfhi(hv[k].x);
        a2 += ww[k] * bflo(hv[k].y); a3 += ww[k] * bfhi(hv[k].y);
      }
    }
    for (; i + 4 <= cnt; i += 4) {
      int ss[4]; float ww[4]; uint2 hv[4];
#pragma unroll
      for (int k = 0; k < 4; ++k) { ss[k] = sidx[wd][i + k]; ww[k] = ew[wd][i + k][gh]; }
#pragma unroll
      for (int k = 0; k < 4; ++k)
        hv[k] = *reinterpret_cast<const uint2*>(hrow + (size_t)ss[k] * 256);
#pragma unroll
      for (int k = 0; k < 4; ++k) {
        a0 += ww[k] * bflo(hv[k].x); a1 += ww[k] * bfhi(hv[k].x);
        a2 += ww[k] * bflo(hv[k].y); a3 += ww[k] * bfhi(hv[k].y);
      }
    }
    for (; i < cnt; ++i) {
      int s = sidx[wd][i];
      float wv = ew[wd][i][gh];
      uint2 hv = *reinterpret_cast<const uint2*>(hrow + (size_t)s * 256);
      a0 += wv * bflo(hv.x);
      a1 += wv * bfhi(hv.x);
      a2 += wv * bflo(hv.y);
      a3 += wv * bfhi(hv.y);
    }
  }

#pragma unroll
  for (int off = 4; off < 64; off <<= 1) zpart += __shfl_xor(zpart, off);
  const float zi = 1.f / (__shfl(zpart, gh) + 1e-16f);

  float4 bi = *reinterpret_cast<const float4*>(bias + c0);
  float v0 = a0 * zi + bi.x, v1 = a1 * zi + bi.y;
  float v2 = a2 * zi + bi.z, v3 = a3 * zi + bi.w;

  float s1 = wave_sum(v0 + v1 + v2 + v3);
  float s2 = wave_sum(v0 * v0 + v1 * v1 + v2 * v2 + v3 * v3);
  float mu = s1 * (1.f / 256.f);
  float var = s2 * (1.f / 256.f) - mu * mu;
  float rstd = rsqrtf(var + 1e-5f);
  float4 ga = *reinterpret_cast<const float4*>(gamma + c0);
  float4 be = *reinterpret_cast<const float4*>(beta + c0);
  float y0 = (v0 - mu) * rstd * ga.x + be.x;
  float y1 = (v1 - mu) * rstd * ga.y + be.y;
  float y2 = (v2 - mu) * rstd * ga.z + be.z;
  float y3 = (v3 - mu) * rstd * ga.w + be.w;
  if (residb) {
    uint2 rv = *reinterpret_cast<const uint2*>(residb + (size_t)d * 256 + c0);
    y0 += bflo(rv.x); y1 += bfhi(rv.x); y2 += bflo(rv.y); y3 += bfhi(rv.y);
  }
  y0 = (y0 > 0.f) ? y0 : expm1f(y0);
  y1 = (y1 > 0.f) ? y1 : expm1f(y1);
  y2 = (y2 > 0.f) ? y2 : expm1f(y2);
  y3 = (y3 > 0.f) ? y3 : expm1f(y3);

  uint2 o;
  o.x = ((unsigned)f2bf(y0)) | (((unsigned)f2bf(y1)) << 16);
  o.y = ((unsigned)f2bf(y2)) | (((unsigned)f2bf(y3)) << 16);
  *reinterpret_cast<uint2*>(outb + (size_t)d * 256 + c0) = o;

  if (score) {
    float4 aww = *reinterpret_cast<const float4*>(aw + c0);
    float sp = wave_sum(y0 * aww.x + y1 * aww.y + y2 * aww.z + y3 * aww.w);
    if (l == 0) score[d] = sp + ab[0];
  }
}

// ---------- pooling: online-softmax partial (one pass over hb2) + combine ----
__global__ __launch_bounds__(256)
void pool_partial_kernel(const ushort* __restrict__ hb2, const float* __restrict__ s,
                         float* __restrict__ part, float* __restrict__ pm,
                         float* __restrict__ pz) {
  __shared__ float red4[4][256];
  __shared__ float mzs[4][2];
  const int t = threadIdx.x, b = blockIdx.x;
  const int c4 = t & 63, rsub = t >> 6;
  float m = -INFINITY, z = 0.f;
  f32x4 acc = (f32x4){0.f, 0.f, 0.f, 0.f};
  for (int n = b * 4 + rsub; n < N_NODES; n += 1024) {
    float sv = s[n];
    float mn = fmaxf(m, sv);
    float f = __expf(m - mn);     // m=-inf first iter -> 0
    float w = __expf(sv - mn);
    z = z * f + w;
    uint2 hv = *reinterpret_cast<const uint2*>(hb2 + (size_t)n * 256 + c4 * 4);
    acc[0] = acc[0] * f + w * bflo(hv.x);
    acc[1] = acc[1] * f + w * bfhi(hv.x);
    acc[2] = acc[2] * f + w * bflo(hv.y);
    acc[3] = acc[3] * f + w * bfhi(hv.y);
    m = mn;
  }
#pragma unroll
  for (int k = 0; k < 4; ++k) red4[rsub][c4 * 4 + k] = acc[k];
  if (c4 == 0) { mzs[rsub][0] = m; mzs[rsub][1] = z; }
  __syncthreads();
  // combine 4 rsub partials (thread t = channel t)
  float M = fmaxf(fmaxf(mzs[0][0], mzs[1][0]), fmaxf(mzs[2][0], mzs[3][0]));
  float e0 = __expf(mzs[0][0] - M), e1 = __expf(mzs[1][0] - M);
  float e2 = __expf(mzs[2][0] - M), e3 = __expf(mzs[3][0] - M);
  float v = red4[0][t] * e0 + red4[1][t] * e1 + red4[2][t] * e2 + red4[3][t] * e3;
  part[b * 256 + t] = v;
  if (t == 0) {
    pm[b] = M;
    pz[b] = mzs[0][1] * e0 + mzs[1][1] * e1 + mzs[2][1] * e2 + mzs[3][1] * e3;
  }
}

__global__ __launch_bounds__(256)
void pool_final_kernel(const float* __restrict__ part, const float* __restrict__ pm,
                       const float* __restrict__ pz, float* __restrict__ out) {
  __shared__ float lm[256], le[256], red[4];
  const int t = threadIdx.x, lane = t & 63, wid = t >> 6;
  lm[t] = pm[t];
  __syncthreads();
  float M = lm[t];
#pragma unroll
  for (int off = 32; off; off >>= 1) M = fmaxf(M, __shfl_xor(M, off));
  if (lane == 0) red[wid] = M;
  __syncthreads();
  M = fmaxf(fmaxf(red[0], red[1]), fmaxf(red[2], red[3]));
  __syncthreads();
  float e = __expf(lm[t] - M);
  le[t] = e;
  float zc = pz[t] * e;
  zc = wave_sum(zc);
  if (lane == 0) red[wid] = zc;
  __syncthreads();
  float Z = red[0] + red[1] + red[2] + red[3];
  float acc = 0.f;
  for (int b = 0; b < 256; ++b) acc += part[b * 256 + t] * le[b];
  out[t] = acc / Z;
}

extern "C" void kernel_launch(void* const* d_in, const int* in_sizes, int n_in,
                              void* d_out, int out_size, void* d_ws, size_t ws_size,
                              hipStream_t stream) {
  const float* x      = (const float*)d_in[0];
  const int*   ei     = (const int*)d_in[1];
  const float* W1     = (const float*)d_in[2];
  const float* b1     = (const float*)d_in[3];
  const float* a_src1 = (const float*)d_in[4];
  const float* a_dst1 = (const float*)d_in[5];
  const float* W2     = (const float*)d_in[6];
  const float* b2     = (const float*)d_in[7];
  const float* a_src2 = (const float*)d_in[8];
  const float* a_dst2 = (const float*)d_in[9];
  const float* g1     = (const float*)d_in[10];
  const float* be1    = (const float*)d_in[11];
  const float* g2     = (const float*)d_in[12];
  const float* be2    = (const float*)d_in[13];
  const float* attn_w = (const float*)d_in[14];
  const float* attn_b = (const float*)d_in[15];
  float* out = (float*)d_out;

  char* p = (char*)d_ws;
  auto alloc = [&](size_t bytes) {
    char* r = p;
    p += (bytes + 255) & ~size_t(255);
    return r;
  };
  ushort* h   = (ushort*)alloc((size_t)N_NODES * 256 * 2);
  ushort* xb  = (ushort*)alloc((size_t)N_NODES * 256 * 2);
  ushort* xb1 = (ushort*)alloc((size_t)N_NODES * 256 * 2);
  ushort* hb2 = (ushort*)alloc((size_t)N_NODES * 256 * 2);
  float* as_  = (float*)alloc((size_t)N_NODES * 4 * 4);
  float* ad_  = (float*)alloc((size_t)N_NODES * 4 * 4);
  float* sbuf = (float*)alloc((size_t)N_NODES * 4);
  float* pm   = (float*)alloc((size_t)256 * 4);
  float* pz   = (float*)alloc((size_t)256 * 4);
  float* part = (float*)alloc((size_t)256 * 256 * 4);
  ushort* wt1 = (ushort*)alloc((size_t)256 * 256 * 2);
  ushort* wt2 = (ushort*)alloc((size_t)256 * 256 * 2);
  int* deg    = (int*)alloc((size_t)N_NODES * 4);
  int* rowp   = (int*)alloc((size_t)(N_NODES + 1) * 4);
  int* cur    = (int*)alloc((size_t)N_NODES * 4);
  int* colb   = (int*)alloc((size_t)TOT_E * 4);

  const int DB = N_NODES / 4;    // 5000
  const int XB = N_NODES * 256 / 8 / 256;  // 2500
  const int SCAN_NB = (N_NODES + 255) / 256;  // deg-zero tail blocks
  const int CONVB = 512 + XB + SCAN_NB;

  conv_inputs_kernel<<<CONVB, 256, 0, stream>>>(W1, W2, x, wt1, wt2, xb, deg);
  hist_kernel<<<EB_K, 256, 0, stream>>>(ei, deg);
  scan_kernel<<<1, 1024, 0, stream>>>(deg, rowp, cur);
  // scatter (CSR finish) overlapped with layer-1 GEMM (independent work)
  scatter_gemm_kernel<<<EB_K + GB_K, 256, 0, stream>>>(
      ei, cur, colb, xb, wt1, a_src1, a_dst1, h, as_, ad_);
  attn_gather_ln_kernel<<<DB, 256, 0, stream>>>(h, as_, ad_, rowp, colb, b1, g1, be1,
                                                nullptr, xb1, nullptr, nullptr, nullptr);
  // layer 2
  gemm_alpha_kernel<<<GB_K, 256, 0, stream>>>(xb1, wt2, a_src2, a_dst2, h, as_, ad_);
  attn_gather_ln_kernel<<<DB, 256, 0, stream>>>(h, as_, ad_, rowp, colb, b2, g2, be2,
                                                xb1, hb2, attn_w, attn_b, sbuf);
  // pooling (2 kernels)
  pool_partial_kernel<<<256, 256, 0, stream>>>(hb2, sbuf, part, pm, pz);
  pool_final_kernel<<<1, 256, 0, stream>>>(part, pm, pz, out);
}

// Round 13
// 172.979 us; speedup vs baseline: 1.0589x; 1.0589x over previous
//
#include <hip/hip_runtime.h>
#include <math.h>

#define N_NODES 20000
#define E_EDGES 320000
#define TOT_E   (E_EDGES + N_NODES)
#define DHID    256
#define NHEAD   4
#define SCAN_NB ((N_NODES + 255) / 256)   // 79
#define SPART   32
#define ECAP    128   // edges staged in LDS per chunk per dst
#define EB_K    ((TOT_E + 255) / 256)     // 1329
#define XB_K    (N_NODES * 256 / 8 / 256) // 2500

typedef float f32x4 __attribute__((ext_vector_type(4)));
typedef short short8 __attribute__((ext_vector_type(8)));
typedef unsigned short ushort;

// ---------- helpers ----------
__device__ __forceinline__ float wave_sum(float v) {
#pragma unroll
  for (int off = 32; off; off >>= 1) v += __shfl_xor(v, off);
  return v;
}
__device__ __forceinline__ ushort f2bf(float f) {  // RNE f32 -> bf16
  unsigned u = __float_as_uint(f);
  u += 0x7fffu + ((u >> 16) & 1u);
  return (ushort)(u >> 16);
}
__device__ __forceinline__ float bflo(unsigned u) {
  return __uint_as_float(u << 16);
}
__device__ __forceinline__ float bfhi(unsigned u) {
  return __uint_as_float(u & 0xffff0000u);
}

// ---------- conversions + hist (deg pre-zeroed by memset) ----------
__global__ __launch_bounds__(256)
void conv_hist_kernel(const float* __restrict__ W1, const float* __restrict__ W2,
                      const float* __restrict__ x, const int* __restrict__ ei,
                      ushort* __restrict__ Wt1, ushort* __restrict__ Wt2,
                      ushort* __restrict__ xb, int* __restrict__ deg) {
  const int b = blockIdx.x;
  if (b < 512) {
    const float* W = (b < 256) ? W1 : W2;
    ushort* Wt = (b < 256) ? Wt1 : Wt2;
    const int n = b & 255;
    const int k = threadIdx.x;
    Wt[n * 256 + k] = f2bf(W[k * 256 + n]);
  } else if (b < 512 + XB_K) {
    int idx = (b - 512) * 256 + threadIdx.x;  // granule of 8
    size_t base = (size_t)idx * 8;
    float4 a = *reinterpret_cast<const float4*>(x + base);
    float4 c = *reinterpret_cast<const float4*>(x + base + 4);
    short8 o;
    o[0] = f2bf(a.x); o[1] = f2bf(a.y); o[2] = f2bf(a.z); o[3] = f2bf(a.w);
    o[4] = f2bf(c.x); o[5] = f2bf(c.y); o[6] = f2bf(c.z); o[7] = f2bf(c.w);
    *reinterpret_cast<short8*>(xb + base) = o;
  } else {
    int e = (b - 512 - XB_K) * 256 + threadIdx.x;
    if (e < TOT_E) {
      int dst = (e < E_EDGES) ? ei[E_EDGES + e] : (e - E_EDGES);
      atomicAdd(&deg[dst], 1);
    }
  }
}

// ---------- scan phase A: per-block sums ----------
__global__ __launch_bounds__(256)
void scan_blocks_kernel(const int* __restrict__ deg, int* __restrict__ bsum) {
  __shared__ int ws[4];
  const int t = threadIdx.x;
  const int i = blockIdx.x * 256 + t;
  int v = (i < N_NODES) ? deg[i] : 0;
  int s = v;
#pragma unroll
  for (int off = 32; off; off >>= 1) s += __shfl_xor(s, off);
  if ((t & 63) == 0) ws[t >> 6] = s;
  __syncthreads();
  if (t == 0) bsum[blockIdx.x] = ws[0] + ws[1] + ws[2] + ws[3];
}

// ---------- scan phase B: self-computed block offset + intra-block scan ----
__global__ __launch_bounds__(256)
void scan_apply_kernel(const int* __restrict__ deg, const int* __restrict__ bsum,
                       int* __restrict__ rowp, int* __restrict__ cur) {
  __shared__ int ws[4], ws2[4];
  const int t = threadIdx.x;
  const int lane = t & 63, w = t >> 6;
  // block offset = sum bsum[0..blockIdx.x)
  int part = 0;
  for (int k = t; k < blockIdx.x; k += 256) part += bsum[k];
#pragma unroll
  for (int off = 32; off; off >>= 1) part += __shfl_xor(part, off);
  if (lane == 0) ws[w] = part;
  __syncthreads();
  const int boff = ws[0] + ws[1] + ws[2] + ws[3];
  const int i = blockIdx.x * 256 + t;
  int v = (i < N_NODES) ? deg[i] : 0;
  int inc = v;
#pragma unroll
  for (int off = 1; off < 64; off <<= 1) {
    int u = __shfl_up(inc, off);
    if (lane >= off) inc += u;
  }
  if (lane == 63) ws2[w] = inc;
  __syncthreads();
  int add = boff;
#pragma unroll
  for (int k = 0; k < 4; ++k)
    if (k < w) add += ws2[k];
  int exc = add + inc - v;
  if (i < N_NODES) {
    rowp[i] = exc;
    cur[i] = exc;
    if (i == N_NODES - 1) rowp[N_NODES] = exc + v;
  }
}

__global__ void scatter_kernel(const int* __restrict__ ei, int* __restrict__ cur,
                               int* __restrict__ colb) {
  int e = blockIdx.x * blockDim.x + threadIdx.x;
  if (e >= TOT_E) return;
  int src, dst;
  if (e < E_EDGES) { src = ei[e]; dst = ei[E_EDGES + e]; }
  else             { src = dst = e - E_EDGES; }
  int pos = atomicAdd(&cur[dst], 1);
  colb[pos] = src;
}

// ---------- bf16-MFMA GEMM (pipelined, barrier-free) + alpha epilogue ----------
__global__ __launch_bounds__(256)
void gemm_alpha_kernel(const ushort* __restrict__ Ab, const ushort* __restrict__ Wt,
                       const float* __restrict__ asrc, const float* __restrict__ adst,
                       ushort* __restrict__ hout, float* __restrict__ as_,
                       float* __restrict__ ad_) {
  __shared__ ushort hs[32 * 256];  // 16 KB repack buffer

  const int t = threadIdx.x;
  const int w = t >> 6;
  const int l = t & 63;
  const int row0 = blockIdx.x * 32;

  const ushort* abase = Ab + (size_t)(row0 + (l & 15)) * 256 + ((l >> 4) * 8);
  const ushort* bbase = Wt + (size_t)(w * 64 + (l & 15)) * 256 + ((l >> 4) * 8);

  f32x4 acc[2][4];
#pragma unroll
  for (int i = 0; i < 2; ++i)
#pragma unroll
    for (int j = 0; j < 4; ++j) acc[i][j] = (f32x4){0.f, 0.f, 0.f, 0.f};

  short8 a0 = *reinterpret_cast<const short8*>(abase);
  short8 a1 = *reinterpret_cast<const short8*>(abase + 16 * 256);
  short8 b0 = *reinterpret_cast<const short8*>(bbase);
  short8 b1 = *reinterpret_cast<const short8*>(bbase + 16 * 256);
  short8 b2 = *reinterpret_cast<const short8*>(bbase + 32 * 256);
  short8 b3 = *reinterpret_cast<const short8*>(bbase + 48 * 256);
#pragma unroll
  for (int kk = 0; kk < 256; kk += 32) {
    short8 na0, na1, nb0, nb1, nb2, nb3;
    if (kk + 32 < 256) {
      na0 = *reinterpret_cast<const short8*>(abase + kk + 32);
      na1 = *reinterpret_cast<const short8*>(abase + 16 * 256 + kk + 32);
      nb0 = *reinterpret_cast<const short8*>(bbase + kk + 32);
      nb1 = *reinterpret_cast<const short8*>(bbase + 16 * 256 + kk + 32);
      nb2 = *reinterpret_cast<const short8*>(bbase + 32 * 256 + kk + 32);
      nb3 = *reinterpret_cast<const short8*>(bbase + 48 * 256 + kk + 32);
    }
    acc[0][0] = __builtin_amdgcn_mfma_f32_16x16x32_bf16(a0, b0, acc[0][0], 0, 0, 0);
    acc[0][1] = __builtin_amdgcn_mfma_f32_16x16x32_bf16(a0, b1, acc[0][1], 0, 0, 0);
    acc[0][2] = __builtin_amdgcn_mfma_f32_16x16x32_bf16(a0, b2, acc[0][2], 0, 0, 0);
    acc[0][3] = __builtin_amdgcn_mfma_f32_16x16x32_bf16(a0, b3, acc[0][3], 0, 0, 0);
    acc[1][0] = __builtin_amdgcn_mfma_f32_16x16x32_bf16(a1, b0, acc[1][0], 0, 0, 0);
    acc[1][1] = __builtin_amdgcn_mfma_f32_16x16x32_bf16(a1, b1, acc[1][1], 0, 0, 0);
    acc[1][2] = __builtin_amdgcn_mfma_f32_16x16x32_bf16(a1, b2, acc[1][2], 0, 0, 0);
    acc[1][3] = __builtin_amdgcn_mfma_f32_16x16x32_bf16(a1, b3, acc[1][3], 0, 0, 0);
    if (kk + 32 < 256) {
      a0 = na0; a1 = na1; b0 = nb0; b1 = nb1; b2 = nb2; b3 = nb3;
    }
  }

  // ---- alpha epilogue ----
  float asj[4], adj[4];
#pragma unroll
  for (int j = 0; j < 4; ++j) {
    asj[j] = asrc[w * 64 + j * 16 + (l & 15)];
    adj[j] = adst[w * 64 + j * 16 + (l & 15)];
  }
#pragma unroll
  for (int i = 0; i < 2; ++i) {
#pragma unroll
    for (int q = 0; q < 4; ++q) {
      float ps = 0.f, pd = 0.f;
#pragma unroll
      for (int j = 0; j < 4; ++j) {
        ps += acc[i][j][q] * asj[j];
        pd += acc[i][j][q] * adj[j];
      }
#pragma unroll
      for (int off = 1; off < 16; off <<= 1) {
        ps += __shfl_xor(ps, off);
        pd += __shfl_xor(pd, off);
      }
      int row = row0 + i * 16 + (l >> 4) * 4 + q;
      if ((l & 15) == 0) {
        as_[row * 4 + w] = ps;
        ad_[row * 4 + w] = pd;
      }
    }
  }

  // ---- h repack: fragments -> LDS bf16 -> coalesced global ----
#pragma unroll
  for (int i = 0; i < 2; ++i)
#pragma unroll
    for (int j = 0; j < 4; ++j)
#pragma unroll
      for (int q = 0; q < 4; ++q) {
        int row = i * 16 + (l >> 4) * 4 + q;
        int col = w * 64 + j * 16 + (l & 15);
        hs[row * 256 + col] = f2bf(acc[i][j][q]);
      }
  __syncthreads();
#pragma unroll
  for (int g = 0; g < 4; ++g) {
    int gi = g * 256 + t;
    int row = gi >> 5;
    int slot = gi & 31;
    *reinterpret_cast<short8*>(hout + (size_t)(row0 + row) * 256 + slot * 8) =
        *reinterpret_cast<const short8*>(&hs[row * 256 + slot * 8]);
  }
}

// ---------- FUSED attn softmax + gather + bias + LN (+resid) + ELU (+score) ----
// Wave per dst (4/block). Shift-invariant softmax (no max pass; e clamped).
// Stage sweep (parallel, 16 edges x 4 heads): w=exp(e) + sidx -> wave-private
// LDS. Serial sweep: LDS-broadcast (sidx,w) + 8-batched independent h loads.
__global__ __launch_bounds__(256)
void attn_gather_ln_kernel(const ushort* __restrict__ h, const float* __restrict__ as_,
                           const float* __restrict__ ad_, const int* __restrict__ rowp,
                           const int* __restrict__ colb, const float* __restrict__ bias,
                           const float* __restrict__ gamma, const float* __restrict__ beta,
                           const ushort* __restrict__ residb, ushort* __restrict__ outb,
                           const float* __restrict__ aw, const float* __restrict__ ab,
                           float* __restrict__ score) {
  __shared__ float ew[4][ECAP][NHEAD];  // 8 KB
  __shared__ int   sidx[4][ECAP];       // 2 KB

  const int t = threadIdx.x;
  const int wd = t >> 6;
  const int d = blockIdx.x * 4 + wd;
  const int l = t & 63;
  const int start = rowp[d];
  const int deg = rowp[d + 1] - start;
  const int* cb = colb + start;

  const int e16 = l >> 2, hh = l & 3;
  const float adv = ad_[d * 4 + hh];
  const int gh = l >> 4;
  const int c0 = l * 4;
  const ushort* hrow = h + c0;

  float zpart = 0.f;
  float a0 = 0.f, a1 = 0.f, a2 = 0.f, a3 = 0.f;

  for (int base = 0; base < deg; base += ECAP) {
    const int cnt = min(deg - base, ECAP);
    for (int i = e16; i < cnt; i += 16) {
      int s = cb[base + i];
      if (hh == 0) sidx[wd][i] = s;
      float e = as_[s * 4 + hh] + adv;
      e = (e >= 0.f) ? e : 0.2f * e;
      e = fminf(e, 60.f);
      float wv = __expf(e);
      ew[wd][i][hh] = wv;
      zpart += wv;
    }
    int i = 0;
    for (; i + 8 <= cnt; i += 8) {
      int ss[8]; float ww[8]; uint2 hv[8];
#pragma unroll
      for (int k = 0; k < 8; ++k) { ss[k] = sidx[wd][i + k]; ww[k] = ew[wd][i + k][gh]; }
#pragma unroll
      for (int k = 0; k < 8; ++k)
        hv[k] = *reinterpret_cast<const uint2*>(hrow + (size_t)ss[k] * 256);
#pragma unroll
      for (int k = 0; k < 8; ++k) {
        a0 += ww[k] * bflo(hv[k].x); a1 += ww[k] * bfhi(hv[k].x);
        a2 += ww[k] * bflo(hv[k].y); a3 += ww[k] * bfhi(hv[k].y);
      }
    }
    for (; i + 4 <= cnt; i += 4) {
      int ss[4]; float ww[4]; uint2 hv[4];
#pragma unroll
      for (int k = 0; k < 4; ++k) { ss[k] = sidx[wd][i + k]; ww[k] = ew[wd][i + k][gh]; }
#pragma unroll
      for (int k = 0; k < 4; ++k)
        hv[k] = *reinterpret_cast<const uint2*>(hrow + (size_t)ss[k] * 256);
#pragma unroll
      for (int k = 0; k < 4; ++k) {
        a0 += ww[k] * bflo(hv[k].x); a1 += ww[k] * bfhi(hv[k].x);
        a2 += ww[k] * bflo(hv[k].y); a3 += ww[k] * bfhi(hv[k].y);
      }
    }
    for (; i < cnt; ++i) {
      int s = sidx[wd][i];
      float wv = ew[wd][i][gh];
      uint2 hv = *reinterpret_cast<const uint2*>(hrow + (size_t)s * 256);
      a0 += wv * bflo(hv.x);
      a1 += wv * bfhi(hv.x);
      a2 += wv * bflo(hv.y);
      a3 += wv * bfhi(hv.y);
    }
  }

#pragma unroll
  for (int off = 4; off < 64; off <<= 1) zpart += __shfl_xor(zpart, off);
  const float zi = 1.f / (__shfl(zpart, gh) + 1e-16f);

  float4 bi = *reinterpret_cast<const float4*>(bias + c0);
  float v0 = a0 * zi + bi.x, v1 = a1 * zi + bi.y;
  float v2 = a2 * zi + bi.z, v3 = a3 * zi + bi.w;

  float s1 = wave_sum(v0 + v1 + v2 + v3);
  float s2 = wave_sum(v0 * v0 + v1 * v1 + v2 * v2 + v3 * v3);
  float mu = s1 * (1.f / 256.f);
  float var = s2 * (1.f / 256.f) - mu * mu;
  float rstd = rsqrtf(var + 1e-5f);
  float4 ga = *reinterpret_cast<const float4*>(gamma + c0);
  float4 be = *reinterpret_cast<const float4*>(beta + c0);
  float y0 = (v0 - mu) * rstd * ga.x + be.x;
  float y1 = (v1 - mu) * rstd * ga.y + be.y;
  float y2 = (v2 - mu) * rstd * ga.z + be.z;
  float y3 = (v3 - mu) * rstd * ga.w + be.w;
  if (residb) {
    uint2 rv = *reinterpret_cast<const uint2*>(residb + (size_t)d * 256 + c0);
    y0 += bflo(rv.x); y1 += bfhi(rv.x); y2 += bflo(rv.y); y3 += bfhi(rv.y);
  }
  y0 = (y0 > 0.f) ? y0 : expm1f(y0);
  y1 = (y1 > 0.f) ? y1 : expm1f(y1);
  y2 = (y2 > 0.f) ? y2 : expm1f(y2);
  y3 = (y3 > 0.f) ? y3 : expm1f(y3);

  uint2 o;
  o.x = ((unsigned)f2bf(y0)) | (((unsigned)f2bf(y1)) << 16);
  o.y = ((unsigned)f2bf(y2)) | (((unsigned)f2bf(y3)) << 16);
  *reinterpret_cast<uint2*>(outb + (size_t)d * 256 + c0) = o;

  if (score) {
    float4 aww = *reinterpret_cast<const float4*>(aw + c0);
    float sp = wave_sum(y0 * aww.x + y1 * aww.y + y2 * aww.z + y3 * aww.w);
    if (l == 0) score[d] = sp + ab[0];
  }
}

// ---------- pooling softmax: parallel partials + combine ----------
__global__ __launch_bounds__(256)
void score_part_kernel(const float* __restrict__ s, float* __restrict__ pm,
                       float* __restrict__ pz) {
  __shared__ float red[4];
  const int t = threadIdx.x, b = blockIdx.x;
  const int lane = t & 63, wid = t >> 6;
  float m = -INFINITY;
  for (int n = b * 256 + t; n < N_NODES; n += SPART * 256) m = fmaxf(m, s[n]);
#pragma unroll
  for (int off = 32; off; off >>= 1) m = fmaxf(m, __shfl_xor(m, off));
  if (lane == 0) red[wid] = m;
  __syncthreads();
  m = fmaxf(fmaxf(red[0], red[1]), fmaxf(red[2], red[3]));
  __syncthreads();
  float z = 0.f;
  for (int n = b * 256 + t; n < N_NODES; n += SPART * 256) z += __expf(s[n] - m);
  z = wave_sum(z);
  if (lane == 0) red[wid] = z;
  __syncthreads();
  if (t == 0) { pm[b] = m; pz[b] = red[0] + red[1] + red[2] + red[3]; }
}

__global__ __launch_bounds__(64)
void score_comb_kernel(const float* __restrict__ pm, const float* __restrict__ pz,
                       float* __restrict__ mz) {
  const int l = threadIdx.x;
  float m = (l < SPART) ? pm[l] : -INFINITY;
#pragma unroll
  for (int off = 32; off; off >>= 1) m = fmaxf(m, __shfl_xor(m, off));
  float z = (l < SPART) ? pz[l] * __expf(pm[l] - m) : 0.f;
  z = wave_sum(z);
  if (l == 0) { mz[0] = m; mz[1] = z; }
}

__global__ __launch_bounds__(256)
void pool_partial_kernel(const ushort* __restrict__ hb2, const float* __restrict__ s,
                         const float* __restrict__ mz, float* __restrict__ part) {
  __shared__ float red4[4][256];
  const int t = threadIdx.x, b = blockIdx.x;
  const int c4 = t & 63, rsub = t >> 6;
  const float m = mz[0];
  const float invz = 1.f / mz[1];
  f32x4 acc = (f32x4){0.f, 0.f, 0.f, 0.f};
  for (int n = b * 4 + rsub; n < N_NODES; n += 1024) {
    float w = __expf(s[n] - m);
    uint2 hv = *reinterpret_cast<const uint2*>(hb2 + (size_t)n * 256 + c4 * 4);
    acc[0] += w * bflo(hv.x);
    acc[1] += w * bfhi(hv.x);
    acc[2] += w * bflo(hv.y);
    acc[3] += w * bfhi(hv.y);
  }
#pragma unroll
  for (int k = 0; k < 4; ++k) red4[rsub][c4 * 4 + k] = acc[k];
  __syncthreads();
  if (t < 256) {
    float v = red4[0][t] + red4[1][t] + red4[2][t] + red4[3][t];
    part[b * 256 + t] = v * invz;
  }
}

__global__ __launch_bounds__(256)
void pool_final_kernel(const float* __restrict__ part, float* __restrict__ out) {
  const int t = threadIdx.x;
  float acc = 0.f;
  for (int b = 0; b < 256; ++b) acc += part[b * 256 + t];
  out[t] = acc;
}

extern "C" void kernel_launch(void* const* d_in, const int* in_sizes, int n_in,
                              void* d_out, int out_size, void* d_ws, size_t ws_size,
                              hipStream_t stream) {
  const float* x      = (const float*)d_in[0];
  const int*   ei     = (const int*)d_in[1];
  const float* W1     = (const float*)d_in[2];
  const float* b1     = (const float*)d_in[3];
  const float* a_src1 = (const float*)d_in[4];
  const float* a_dst1 = (const float*)d_in[5];
  const float* W2     = (const float*)d_in[6];
  const float* b2     = (const float*)d_in[7];
  const float* a_src2 = (const float*)d_in[8];
  const float* a_dst2 = (const float*)d_in[9];
  const float* g1     = (const float*)d_in[10];
  const float* be1    = (const float*)d_in[11];
  const float* g2     = (const float*)d_in[12];
  const float* be2    = (const float*)d_in[13];
  const float* attn_w = (const float*)d_in[14];
  const float* attn_b = (const float*)d_in[15];
  float* out = (float*)d_out;

  char* p = (char*)d_ws;
  auto alloc = [&](size_t bytes) {
    char* r = p;
    p += (bytes + 255) & ~size_t(255);
    return r;
  };
  ushort* h   = (ushort*)alloc((size_t)N_NODES * 256 * 2);
  ushort* xb  = (ushort*)alloc((size_t)N_NODES * 256 * 2);
  ushort* xb1 = (ushort*)alloc((size_t)N_NODES * 256 * 2);
  ushort* hb2 = (ushort*)alloc((size_t)N_NODES * 256 * 2);
  float* as_  = (float*)alloc((size_t)N_NODES * 4 * 4);
  float* ad_  = (float*)alloc((size_t)N_NODES * 4 * 4);
  float* sbuf = (float*)alloc((size_t)N_NODES * 4);
  float* mz   = (float*)alloc(256);
  float* pm   = (float*)alloc((size_t)SPART * 4);
  float* pz   = (float*)alloc((size_t)SPART * 4);
  float* part = (float*)alloc((size_t)256 * 256 * 4);
  ushort* wt1 = (ushort*)alloc((size_t)256 * 256 * 2);
  ushort* wt2 = (ushort*)alloc((size_t)256 * 256 * 2);
  int* deg    = (int*)alloc((size_t)N_NODES * 4);
  int* rowp   = (int*)alloc((size_t)(N_NODES + 1) * 4);
  int* cur    = (int*)alloc((size_t)N_NODES * 4);
  int* colb   = (int*)alloc((size_t)TOT_E * 4);
  int* bsum   = (int*)alloc((size_t)SCAN_NB * 4);

  const int GB = N_NODES / 32;   // 625
  const int DB = N_NODES / 4;    // 5000
  const int CONVB = 512 + XB_K + EB_K;

  hipMemsetAsync(deg, 0, (size_t)N_NODES * 4, stream);
  conv_hist_kernel<<<CONVB, 256, 0, stream>>>(W1, W2, x, ei, wt1, wt2, xb, deg);
  scan_blocks_kernel<<<SCAN_NB, 256, 0, stream>>>(deg, bsum);
  scan_apply_kernel<<<SCAN_NB, 256, 0, stream>>>(deg, bsum, rowp, cur);
  scatter_kernel<<<EB_K, 256, 0, stream>>>(ei, cur, colb);

  // layer 1
  gemm_alpha_kernel<<<GB, 256, 0, stream>>>(xb, wt1, a_src1, a_dst1, h, as_, ad_);
  attn_gather_ln_kernel<<<DB, 256, 0, stream>>>(h, as_, ad_, rowp, colb, b1, g1, be1,
                                                nullptr, xb1, nullptr, nullptr, nullptr);
  // layer 2
  gemm_alpha_kernel<<<GB, 256, 0, stream>>>(xb1, wt2, a_src2, a_dst2, h, as_, ad_);
  attn_gather_ln_kernel<<<DB, 256, 0, stream>>>(h, as_, ad_, rowp, colb, b2, g2, be2,
                                                xb1, hb2, attn_w, attn_b, sbuf);
  // pooling
  score_part_kernel<<<SPART, 256, 0, stream>>>(sbuf, pm, pz);
  score_comb_kernel<<<1, 64, 0, stream>>>(pm, pz, mz);
  pool_partial_kernel<<<256, 256, 0, stream>>>(hb2, sbuf, mz, part);
  pool_final_kernel<<<1, 256, 0, stream>>>(part, out);
}